// Round 1
// baseline (48784.140 us; speedup 1.0000x reference)
//
#include <hip/hip_runtime.h>
#include <hip/hip_fp16.h>

#define T_STEPS 2048
#define B_SZ 128
#define I_SZ 10
#define H_SZ 512

#define BSPLIT 4
#define HSPLIT 32
#define NWG (BSPLIT * HSPLIT)   // 128 workgroups
#define BTILE (B_SZ / BSPLIT)   // 32 batch rows per wg
#define HTILE (H_SZ / HSPLIT)   // 16 hidden cols per wg

typedef _Float16 f16x8 __attribute__((ext_vector_type(8)));
typedef float f32x4 __attribute__((ext_vector_type(4)));

__global__ void init_flags_kernel(int* flags) {
    int i = threadIdx.x;
    if (i < NWG) flags[i] = 0;
}

// Persistent LSTM kernel: 128 wgs, each owns a (32 x 16) tile of h/c for all
// 2048 timesteps. W_hh fp16 fragments live in registers; h is exchanged
// device-wide each step through a double-buffered fp16 buffer in d_ws,
// synchronized with per-wg monotonic flags (agent-scope atomics + fences).
__global__ __launch_bounds__(256, 1) void lstm_persistent(
    const float* __restrict__ x,     // [T,B,I]
    const float* __restrict__ hx,    // [B,H]
    const float* __restrict__ cx,    // [B,H]
    const float* __restrict__ W_ih,  // [4H,I]
    const float* __restrict__ W_hh,  // [4H,H]
    const float* __restrict__ b_ih,  // [4H]
    const float* __restrict__ b_hh,  // [4H]
    float* __restrict__ out,         // [3*B*H] = h, h, c
    int* flags,                      // [NWG]
    _Float16* h_buf)                 // [2][B][H] fp16
{
    __shared__ float x_s[BTILE * I_SZ];          // 320 f32
    __shared__ float lds_g[4][BTILE][HTILE];     // 8 KB gate exchange

    const int wg   = blockIdx.x;
    const int bs   = wg >> 5;          // batch split index (0..3)
    const int hs   = wg & 31;          // hidden split index (0..31)
    const int tid  = threadIdx.x;
    const int wid  = tid >> 6;         // wave 0..3
    const int lane = tid & 63;
    const int m    = wid & 1;          // m-fragment (16 batch rows each)
    const int gp   = wid >> 1;         // gate pair: 0 -> {i,f}, 1 -> {g,o}

    const int fr_col = lane & 15;      // row/col-within-fragment
    const int fr_kg  = lane >> 4;      // k-group (0..3)

    // A operand rows (batch) for this wave's fragment loads
    const int a_row = bs * BTILE + m * 16 + fr_col;

    // gate columns of W_hh handled by this lane (two n-fragments)
    const int gate0 = 2 * gp;          // 0 (i) or 2 (g)
    const int gate1 = 2 * gp + 1;      // 1 (f) or 3 (o)
    const int hc_g  = hs * HTILE + fr_col;
    const int gc0   = gate0 * H_SZ + hc_g;
    const int gc1   = gate1 * H_SZ + hc_g;

    // ---- preload W_hh fragments (B operand: B[k][col] = W_hh[gc][k]), fp16
    f16x8 wf0[16], wf1[16];
    #pragma unroll
    for (int kk = 0; kk < 16; ++kk) {
        const int k0 = kk * 32 + fr_kg * 8;
        const float* p0 = W_hh + (size_t)gc0 * H_SZ + k0;
        const float* p1 = W_hh + (size_t)gc1 * H_SZ + k0;
        f16x8 w0, w1;
        #pragma unroll
        for (int e = 0; e < 8; ++e) {
            w0[e] = (_Float16)p0[e];
            w1[e] = (_Float16)p1[e];
        }
        wf0[kk] = w0;
        wf1[kk] = w1;
    }

    // ---- preload W_ih rows + combined bias (fp32, used on VALU each step)
    float wih0[I_SZ], wih1[I_SZ];
    #pragma unroll
    for (int i = 0; i < I_SZ; ++i) {
        wih0[i] = W_ih[gc0 * I_SZ + i];
        wih1[i] = W_ih[gc1 * I_SZ + i];
    }
    const float bias0 = b_ih[gc0] + b_hh[gc0];
    const float bias1 = b_ih[gc1] + b_hh[gc1];

    // ---- per-thread persistent state: 2 (b,hc) cells per thread
    const int v0 = tid * 2, v1 = tid * 2 + 1;       // 0..511
    const int cb0 = v0 >> 4, chc0 = v0 & 15;
    const int cb1 = v1 >> 4, chc1 = v1 & 15;
    const int gb0 = bs * BTILE + cb0, ghc0 = hs * HTILE + chc0;
    const int gb1 = bs * BTILE + cb1, ghc1 = hs * HTILE + chc1;

    float c0 = cx[gb0 * H_SZ + ghc0];
    float c1 = cx[gb1 * H_SZ + ghc1];
    float h0 = hx[gb0 * H_SZ + ghc0];
    float h1 = hx[gb1 * H_SZ + ghc1];

    // ---- publish initial h (h_pub[0] -> buffer 0) for our slice
    h_buf[gb0 * H_SZ + ghc0] = (_Float16)h0;
    h_buf[gb1 * H_SZ + ghc1] = (_Float16)h1;
    __syncthreads();
    if (tid == 0) {
        __threadfence();
        __hip_atomic_store(&flags[wg], 1, __ATOMIC_RELEASE, __HIP_MEMORY_SCOPE_AGENT);
    }

    #pragma unroll 1
    for (int t = 0; t < T_STEPS; ++t) {
        // -- stage x_t tile to LDS (independent of h; hides under the poll)
        {
            const float* xp = x + (size_t)t * (B_SZ * I_SZ) + bs * (BTILE * I_SZ);
            x_s[tid] = xp[tid];
            if (tid < BTILE * I_SZ - 256) x_s[tid + 256] = xp[tid + 256];
        }
        __syncthreads();

        // -- wait until all wgs have published h_pub[t]  (flags[*] >= t+1).
        //    This also guarantees buffer (t+1)&1 is safe to overwrite.
        {
            const int tgt = t + 1;
            for (;;) {
                int f0 = __hip_atomic_load(&flags[lane],      __ATOMIC_RELAXED, __HIP_MEMORY_SCOPE_AGENT);
                int f1 = __hip_atomic_load(&flags[lane + 64], __ATOMIC_RELAXED, __HIP_MEMORY_SCOPE_AGENT);
                if (__all(f0 >= tgt && f1 >= tgt)) break;
                __builtin_amdgcn_s_sleep(8);
                __threadfence();   // invalidate caches so the retry sees fresh flags
            }
            __threadfence();       // acquire: make published h visible
        }

        // -- accumulator init: bias + x_t @ W_ih^T (K=10, fp32 VALU)
        f32x4 acc0, acc1;
        #pragma unroll
        for (int r = 0; r < 4; ++r) {
            const int bl = m * 16 + fr_kg * 4 + r;   // batch row within tile
            float s0 = bias0, s1 = bias1;
            #pragma unroll
            for (int i = 0; i < I_SZ; ++i) {
                const float xv = x_s[bl * I_SZ + i];
                s0 += xv * wih0[i];
                s1 += xv * wih1[i];
            }
            acc0[r] = s0;
            acc1[r] = s1;
        }

        // -- h @ W_hh^T via MFMA 16x16x32 f16, K=512 (16 k-steps)
        {
            const _Float16* hb = h_buf + (size_t)(t & 1) * (B_SZ * H_SZ);
            const _Float16* ap = hb + (size_t)a_row * H_SZ + fr_kg * 8;
            #pragma unroll
            for (int kk = 0; kk < 16; ++kk) {
                f16x8 a = *(const f16x8*)(ap + kk * 32);
                acc0 = __builtin_amdgcn_mfma_f32_16x16x32_f16(a, wf0[kk], acc0, 0, 0, 0);
                acc1 = __builtin_amdgcn_mfma_f32_16x16x32_f16(a, wf1[kk], acc1, 0, 0, 0);
            }
        }

        // -- nonlinearities, exchange gate values through LDS
        #pragma unroll
        for (int r = 0; r < 4; ++r) {
            const int bl = m * 16 + fr_kg * 4 + r;
            const float p0 = acc0[r], p1 = acc1[r];
            float n0, n1;
            if (gp == 0) {          // gates i, f : sigmoid
                n0 = 1.f / (1.f + __expf(-p0));
                n1 = 1.f / (1.f + __expf(-p1));
            } else {                // gate g: tanh, gate o: sigmoid
                const float e = __expf(-2.f * p0);
                n0 = (1.f - e) / (1.f + e);
                n1 = 1.f / (1.f + __expf(-p1));
            }
            lds_g[gate0][bl][fr_col] = n0;
            lds_g[gate1][bl][fr_col] = n1;
        }
        __syncthreads();

        // -- update owned c/h cells, publish h_pub[t+1]
        {
            const float ig0 = lds_g[0][cb0][chc0], fg0 = lds_g[1][cb0][chc0];
            const float gg0 = lds_g[2][cb0][chc0], og0 = lds_g[3][cb0][chc0];
            const float ig1 = lds_g[0][cb1][chc1], fg1 = lds_g[1][cb1][chc1];
            const float gg1 = lds_g[2][cb1][chc1], og1 = lds_g[3][cb1][chc1];
            c0 = fg0 * c0 + ig0 * gg0;
            c1 = fg1 * c1 + ig1 * gg1;
            const float e0 = __expf(-2.f * c0), e1 = __expf(-2.f * c1);
            h0 = og0 * (1.f - e0) / (1.f + e0);
            h1 = og1 * (1.f - e1) / (1.f + e1);
            if (t < T_STEPS - 1) {
                _Float16* hbn = h_buf + (size_t)((t + 1) & 1) * (B_SZ * H_SZ);
                hbn[gb0 * H_SZ + ghc0] = (_Float16)h0;
                hbn[gb1 * H_SZ + ghc1] = (_Float16)h1;
            }
        }
        __syncthreads();   // all stores done (compiler drains vmcnt before barrier)
        if (tid == 0 && t < T_STEPS - 1) {
            __threadfence();
            __hip_atomic_store(&flags[wg], t + 2, __ATOMIC_RELEASE, __HIP_MEMORY_SCOPE_AGENT);
        }
    }

    // ---- final outputs: (h, h, c) each [B,H] f32
    out[gb0 * H_SZ + ghc0] = h0;
    out[gb1 * H_SZ + ghc1] = h1;
    out[B_SZ * H_SZ + gb0 * H_SZ + ghc0] = h0;
    out[B_SZ * H_SZ + gb1 * H_SZ + ghc1] = h1;
    out[2 * B_SZ * H_SZ + gb0 * H_SZ + ghc0] = c0;
    out[2 * B_SZ * H_SZ + gb1 * H_SZ + ghc1] = c1;
}

extern "C" void kernel_launch(void* const* d_in, const int* in_sizes, int n_in,
                              void* d_out, int out_size, void* d_ws, size_t ws_size,
                              hipStream_t stream) {
    const float* x    = (const float*)d_in[0];
    const float* hx   = (const float*)d_in[1];
    const float* cx   = (const float*)d_in[2];
    const float* W_ih = (const float*)d_in[3];
    const float* W_hh = (const float*)d_in[4];
    const float* b_ih = (const float*)d_in[5];
    const float* b_hh = (const float*)d_in[6];
    float* out = (float*)d_out;

    // workspace layout: [0,512) flags, [1024, 1024 + 2*B*H*2) fp16 h double-buffer
    char* ws = (char*)d_ws;
    int* flags = (int*)ws;
    _Float16* h_buf = (_Float16*)(ws + 1024);

    init_flags_kernel<<<1, 128, 0, stream>>>(flags);
    lstm_persistent<<<NWG, 256, 0, stream>>>(x, hx, cx, W_ih, W_hh, b_ih, b_hh,
                                             out, flags, h_buf);
}

// Round 2
// 21467.569 us; speedup vs baseline: 2.2725x; 2.2725x over previous
//
#include <hip/hip_runtime.h>
#include <hip/hip_fp16.h>

#define T_STEPS 2048
#define B_SZ 128
#define I_SZ 10
#define H_SZ 512

#define BSPLIT 4
#define HSPLIT 32
#define NWG (BSPLIT * HSPLIT)   // 128 workgroups
#define BTILE (B_SZ / BSPLIT)   // 32 batch rows per wg
#define HTILE (H_SZ / HSPLIT)   // 16 hidden cols per wg

typedef _Float16 f16x8 __attribute__((ext_vector_type(8)));
typedef float f32x4 __attribute__((ext_vector_type(4)));

__global__ void init_flags_kernel(int* flags) {
    int i = threadIdx.x;
    if (i < NWG) flags[i] = 0;
}

// Persistent LSTM kernel: 128 wgs, each owns a (32 x 16) tile of h/c for all
// 2048 timesteps. W_hh fp16 fragments live in registers; h is exchanged each
// step through a double-buffered fp16 buffer in d_ws. Sync is a 32-wg GROUP
// barrier (only wgs sharing a batch-split exchange h): monotonic per-wg flags,
// release-store + fence-free sc0/sc1 polling + one acquire fence.
__global__ __launch_bounds__(256, 1) void lstm_persistent(
    const float* __restrict__ x,     // [T,B,I]
    const float* __restrict__ hx,    // [B,H]
    const float* __restrict__ cx,    // [B,H]
    const float* __restrict__ W_ih,  // [4H,I]
    const float* __restrict__ W_hh,  // [4H,H]
    const float* __restrict__ b_ih,  // [4H]
    const float* __restrict__ b_hh,  // [4H]
    float* __restrict__ out,         // [3*B*H] = h, h, c
    int* flags,                      // [NWG]
    _Float16* h_buf)                 // [2][B][H] fp16
{
    __shared__ float x_s[BTILE * I_SZ];          // 320 f32
    __shared__ float lds_g[4][BTILE][HTILE];     // 8 KB gate exchange

    const int wg   = blockIdx.x;
    const int bs   = wg >> 5;          // batch split index (0..3)
    const int hs   = wg & 31;          // hidden split index (0..31)
    const int grp  = bs << 5;          // first wg of our group
    const int tid  = threadIdx.x;
    const int wid  = tid >> 6;         // wave 0..3
    const int lane = tid & 63;
    const int m    = wid & 1;          // m-fragment (16 batch rows each)
    const int gp   = wid >> 1;         // gate pair: 0 -> {i,f}, 1 -> {g,o}

    const int fr_col = lane & 15;      // row/col-within-fragment
    const int fr_kg  = lane >> 4;      // k-group (0..3)

    // A operand rows (batch) for this wave's fragment loads
    const int a_row = bs * BTILE + m * 16 + fr_col;

    // gate columns of W_hh handled by this lane (two n-fragments)
    const int gate0 = 2 * gp;          // 0 (i) or 2 (g)
    const int gate1 = 2 * gp + 1;      // 1 (f) or 3 (o)
    const int hc_g  = hs * HTILE + fr_col;
    const int gc0   = gate0 * H_SZ + hc_g;
    const int gc1   = gate1 * H_SZ + hc_g;

    // ---- preload W_hh fragments (B operand: B[k][col] = W_hh[gc][k]), fp16
    f16x8 wf0[16], wf1[16];
    #pragma unroll
    for (int kk = 0; kk < 16; ++kk) {
        const int k0 = kk * 32 + fr_kg * 8;
        const float* p0 = W_hh + (size_t)gc0 * H_SZ + k0;
        const float* p1 = W_hh + (size_t)gc1 * H_SZ + k0;
        f16x8 w0, w1;
        #pragma unroll
        for (int e = 0; e < 8; ++e) {
            w0[e] = (_Float16)p0[e];
            w1[e] = (_Float16)p1[e];
        }
        wf0[kk] = w0;
        wf1[kk] = w1;
    }

    // ---- preload W_ih rows + combined bias (fp32, used on VALU each step)
    float wih0[I_SZ], wih1[I_SZ];
    #pragma unroll
    for (int i = 0; i < I_SZ; ++i) {
        wih0[i] = W_ih[gc0 * I_SZ + i];
        wih1[i] = W_ih[gc1 * I_SZ + i];
    }
    const float bias0 = b_ih[gc0] + b_hh[gc0];
    const float bias1 = b_ih[gc1] + b_hh[gc1];

    // ---- per-thread persistent state: 2 (b,hc) cells per thread
    const int v0 = tid * 2, v1 = tid * 2 + 1;       // 0..511
    const int cb0 = v0 >> 4, chc0 = v0 & 15;
    const int cb1 = v1 >> 4, chc1 = v1 & 15;
    const int gb0 = bs * BTILE + cb0, ghc0 = hs * HTILE + chc0;
    const int gb1 = bs * BTILE + cb1, ghc1 = hs * HTILE + chc1;

    float c0 = cx[gb0 * H_SZ + ghc0];
    float c1 = cx[gb1 * H_SZ + ghc1];
    float h0 = hx[gb0 * H_SZ + ghc0];
    float h1 = hx[gb1 * H_SZ + ghc1];

    // ---- publish initial h (h_pub[0] -> buffer 0) for our slice
    h_buf[gb0 * H_SZ + ghc0] = (_Float16)h0;
    h_buf[gb1 * H_SZ + ghc1] = (_Float16)h1;
    __syncthreads();
    if (tid == 0) {
        __hip_atomic_store(&flags[wg], 1, __ATOMIC_RELEASE, __HIP_MEMORY_SCOPE_AGENT);
    }

    #pragma unroll 1
    for (int t = 0; t < T_STEPS; ++t) {
        // -- stage x_t tile to LDS (independent of h)
        {
            const float* xp = x + (size_t)t * (B_SZ * I_SZ) + bs * (BTILE * I_SZ);
            x_s[tid] = xp[tid];
            if (tid < BTILE * I_SZ - 256) x_s[tid + 256] = xp[tid + 256];
        }
        __syncthreads();

        // -- accumulator init: bias + x_t @ W_ih^T (K=10, fp32 VALU).
        //    h-independent, so done BEFORE the barrier wait.
        f32x4 acc0, acc1;
        #pragma unroll
        for (int r = 0; r < 4; ++r) {
            const int bl = m * 16 + fr_kg * 4 + r;   // batch row within tile
            float s0 = bias0, s1 = bias1;
            #pragma unroll
            for (int i = 0; i < I_SZ; ++i) {
                const float xv = x_s[bl * I_SZ + i];
                s0 += xv * wih0[i];
                s1 += xv * wih1[i];
            }
            acc0[r] = s0;
            acc1[r] = s1;
        }

        // -- group barrier: wait until the 32 wgs of our batch-split group
        //    have published h_pub[t] (flags >= t+1). Relaxed agent loads
        //    (sc0/sc1, cache-bypassing) — NO fence in the poll loop.
        {
            const int tgt = t + 1;
            int spin = 0;
            for (;;) {
                int f = __hip_atomic_load(&flags[grp + (lane & 31)],
                                          __ATOMIC_RELAXED, __HIP_MEMORY_SCOPE_AGENT);
                if (__all(f >= tgt)) break;
                __builtin_amdgcn_s_sleep(2);
                if ((++spin & 63) == 0) __threadfence();  // failsafe only
            }
            __builtin_amdgcn_fence(__ATOMIC_ACQUIRE, "agent");  // make h visible
        }

        // -- h @ W_hh^T via MFMA 16x16x32 f16, K=512 (16 k-steps)
        {
            const _Float16* hb = h_buf + (size_t)(t & 1) * (B_SZ * H_SZ);
            const _Float16* ap = hb + (size_t)a_row * H_SZ + fr_kg * 8;
            #pragma unroll
            for (int kk = 0; kk < 16; ++kk) {
                f16x8 a = *(const f16x8*)(ap + kk * 32);
                acc0 = __builtin_amdgcn_mfma_f32_16x16x32_f16(a, wf0[kk], acc0, 0, 0, 0);
                acc1 = __builtin_amdgcn_mfma_f32_16x16x32_f16(a, wf1[kk], acc1, 0, 0, 0);
            }
        }

        // -- nonlinearities, exchange gate values through LDS
        #pragma unroll
        for (int r = 0; r < 4; ++r) {
            const int bl = m * 16 + fr_kg * 4 + r;
            const float p0 = acc0[r], p1 = acc1[r];
            float n0, n1;
            if (gp == 0) {          // gates i, f : sigmoid
                n0 = 1.f / (1.f + __expf(-p0));
                n1 = 1.f / (1.f + __expf(-p1));
            } else {                // gate g: tanh, gate o: sigmoid
                const float e = __expf(-2.f * p0);
                n0 = (1.f - e) / (1.f + e);
                n1 = 1.f / (1.f + __expf(-p1));
            }
            lds_g[gate0][bl][fr_col] = n0;
            lds_g[gate1][bl][fr_col] = n1;
        }
        __syncthreads();

        // -- update owned c/h cells, publish h_pub[t+1]
        {
            const float ig0 = lds_g[0][cb0][chc0], fg0 = lds_g[1][cb0][chc0];
            const float gg0 = lds_g[2][cb0][chc0], og0 = lds_g[3][cb0][chc0];
            const float ig1 = lds_g[0][cb1][chc1], fg1 = lds_g[1][cb1][chc1];
            const float gg1 = lds_g[2][cb1][chc1], og1 = lds_g[3][cb1][chc1];
            c0 = fg0 * c0 + ig0 * gg0;
            c1 = fg1 * c1 + ig1 * gg1;
            const float e0 = __expf(-2.f * c0), e1 = __expf(-2.f * c1);
            h0 = og0 * (1.f - e0) / (1.f + e0);
            h1 = og1 * (1.f - e1) / (1.f + e1);
            if (t < T_STEPS - 1) {
                _Float16* hbn = h_buf + (size_t)((t + 1) & 1) * (B_SZ * H_SZ);
                hbn[gb0 * H_SZ + ghc0] = (_Float16)h0;
                hbn[gb1 * H_SZ + ghc1] = (_Float16)h1;
            }
        }
        __syncthreads();   // all h stores issued+drained (vmcnt) before release
        if (tid == 0 && t < T_STEPS - 1) {
            __hip_atomic_store(&flags[wg], t + 2, __ATOMIC_RELEASE, __HIP_MEMORY_SCOPE_AGENT);
        }
    }

    // ---- final outputs: (h, h, c) each [B,H] f32
    out[gb0 * H_SZ + ghc0] = h0;
    out[gb1 * H_SZ + ghc1] = h1;
    out[B_SZ * H_SZ + gb0 * H_SZ + ghc0] = h0;
    out[B_SZ * H_SZ + gb1 * H_SZ + ghc1] = h1;
    out[2 * B_SZ * H_SZ + gb0 * H_SZ + ghc0] = c0;
    out[2 * B_SZ * H_SZ + gb1 * H_SZ + ghc1] = c1;
}

extern "C" void kernel_launch(void* const* d_in, const int* in_sizes, int n_in,
                              void* d_out, int out_size, void* d_ws, size_t ws_size,
                              hipStream_t stream) {
    const float* x    = (const float*)d_in[0];
    const float* hx   = (const float*)d_in[1];
    const float* cx   = (const float*)d_in[2];
    const float* W_ih = (const float*)d_in[3];
    const float* W_hh = (const float*)d_in[4];
    const float* b_ih = (const float*)d_in[5];
    const float* b_hh = (const float*)d_in[6];
    float* out = (float*)d_out;

    // workspace layout: [0,512) flags, [1024, 1024 + 2*B*H*2) fp16 h double-buffer
    char* ws = (char*)d_ws;
    int* flags = (int*)ws;
    _Float16* h_buf = (_Float16*)(ws + 1024);

    init_flags_kernel<<<1, 128, 0, stream>>>(flags);
    lstm_persistent<<<NWG, 256, 0, stream>>>(x, hx, cx, W_ih, W_hh, b_ih, b_hh,
                                             out, flags, h_buf);
}

// Round 3
// 13679.755 us; speedup vs baseline: 3.5662x; 1.5693x over previous
//
#include <hip/hip_runtime.h>
#include <hip/hip_fp16.h>

#define T_STEPS 2048
#define B_SZ 128
#define I_SZ 10
#define H_SZ 512

#define BSPLIT 4
#define HSPLIT 32
#define NWG (BSPLIT * HSPLIT)   // 128 workgroups
#define BTILE (B_SZ / BSPLIT)   // 32 batch rows per wg
#define HTILE (H_SZ / HSPLIT)   // 16 hidden cols per wg

typedef _Float16 f16x8 __attribute__((ext_vector_type(8)));
typedef float f32x4 __attribute__((ext_vector_type(4)));

__global__ void init_flags_kernel(int* flags) {
    int i = threadIdx.x;
    if (i < NWG) flags[i] = 0;
}

// Persistent LSTM: 128 wgs, each owns a (32 x 16) tile of h/c for all 2048
// steps. W_hh fp16 fragments register-resident. h exchanged per step through
// a double-buffered fp16 buffer in d_ws.
//
// Sync design (R3): ZERO cache-wide maintenance ops. All cross-wg data
// (h_buf, flags) uses relaxed AGENT-scope atomics, which emit per-access
// sc0/sc1 (L1-bypass, device-coherent at the memory-side LLC). Ordering:
// producer drains its h stores (vmcnt0 + __syncthreads) before the relaxed
// flag store; consumer polls flags then issues LLC-coherent h loads. No
// buffer_inv / buffer_wb anywhere -> x/W stay L2-resident.
__global__ __launch_bounds__(256, 1) void lstm_persistent(
    const float* __restrict__ x,     // [T,B,I]
    const float* __restrict__ hx,    // [B,H]
    const float* __restrict__ cx,    // [B,H]
    const float* __restrict__ W_ih,  // [4H,I]
    const float* __restrict__ W_hh,  // [4H,H]
    const float* __restrict__ b_ih,  // [4H]
    const float* __restrict__ b_hh,  // [4H]
    float* __restrict__ out,         // [3*B*H] = h, h, c
    int* flags,                      // [NWG]
    _Float16* h_buf)                 // [2][B][H] fp16
{
    __shared__ float x_s[BTILE * I_SZ];          // 320 f32
    __shared__ float lds_g[4][BTILE][HTILE];     // 8 KB gate exchange

    const int wg   = blockIdx.x;
    const int bs   = wg >> 5;          // batch split index (0..3)
    const int hs   = wg & 31;          // hidden split index (0..31)
    const int grp  = bs << 5;          // first wg of our 32-wg group
    const int tid  = threadIdx.x;
    const int wid  = tid >> 6;         // wave 0..3
    const int lane = tid & 63;
    const int m    = wid & 1;          // m-fragment (16 batch rows each)
    const int gp   = wid >> 1;         // gate pair: 0 -> {i,f}, 1 -> {g,o}

    const int fr_col = lane & 15;      // row/col-within-fragment
    const int fr_kg  = lane >> 4;      // k-group (0..3)

    // A operand row (batch) for this lane's fragment loads
    const int a_row = bs * BTILE + m * 16 + fr_col;

    // gate columns of W_hh handled by this lane (two n-fragments)
    const int gate0 = 2 * gp;          // 0 (i) or 2 (g)
    const int gate1 = 2 * gp + 1;      // 1 (f) or 3 (o)
    const int hc_g  = hs * HTILE + fr_col;
    const int gc0   = gate0 * H_SZ + hc_g;
    const int gc1   = gate1 * H_SZ + hc_g;

    // ---- preload W_hh fragments (B operand: B[k][col] = W_hh[gc][k]), fp16
    f16x8 wf0[16], wf1[16];
    #pragma unroll
    for (int kk = 0; kk < 16; ++kk) {
        const int k0 = kk * 32 + fr_kg * 8;
        const float* p0 = W_hh + (size_t)gc0 * H_SZ + k0;
        const float* p1 = W_hh + (size_t)gc1 * H_SZ + k0;
        f16x8 w0, w1;
        #pragma unroll
        for (int e = 0; e < 8; ++e) {
            w0[e] = (_Float16)p0[e];
            w1[e] = (_Float16)p1[e];
        }
        wf0[kk] = w0;
        wf1[kk] = w1;
    }

    // ---- preload W_ih rows + combined bias (fp32, used on VALU each step)
    float wih0[I_SZ], wih1[I_SZ];
    #pragma unroll
    for (int i = 0; i < I_SZ; ++i) {
        wih0[i] = W_ih[gc0 * I_SZ + i];
        wih1[i] = W_ih[gc1 * I_SZ + i];
    }
    const float bias0 = b_ih[gc0] + b_hh[gc0];
    const float bias1 = b_ih[gc1] + b_hh[gc1];

    // ---- per-thread persistent state: 2 ADJACENT (b,hc) cells per thread
    const int v0 = tid * 2;                      // 0..510 even
    const int cb0 = v0 >> 4, chc0 = v0 & 15;     // chc0 even, pair is (chc0, chc0+1)
    const int gb0 = bs * BTILE + cb0;
    const int ghc0 = hs * HTILE + chc0;

    float c0 = cx[gb0 * H_SZ + ghc0];
    float c1 = cx[gb0 * H_SZ + ghc0 + 1];
    float h0 = hx[gb0 * H_SZ + ghc0];
    float h1 = hx[gb0 * H_SZ + ghc0 + 1];

    // ---- publish initial h (buffer 0): packed 2xfp16, agent-scope relaxed
    {
        union { _Float16 hp[2]; unsigned u; } pk;
        pk.hp[0] = (_Float16)h0; pk.hp[1] = (_Float16)h1;
        __hip_atomic_store((unsigned*)&h_buf[gb0 * H_SZ + ghc0], pk.u,
                           __ATOMIC_RELAXED, __HIP_MEMORY_SCOPE_AGENT);
    }
    asm volatile("s_waitcnt vmcnt(0)" ::: "memory");
    __syncthreads();
    if (tid == 0) {
        __hip_atomic_store(&flags[wg], 1, __ATOMIC_RELAXED, __HIP_MEMORY_SCOPE_AGENT);
    }

    #pragma unroll 1
    for (int t = 0; t < T_STEPS; ++t) {
        // -- stage x_t tile to LDS (h-independent; plain cached loads)
        {
            const float* xp = x + (size_t)t * (B_SZ * I_SZ) + bs * (BTILE * I_SZ);
            x_s[tid] = xp[tid];
            if (tid < BTILE * I_SZ - 256) x_s[tid + 256] = xp[tid + 256];
        }
        __syncthreads();

        // -- accumulator init: bias + x_t @ W_ih^T (K=10, fp32 VALU), pre-poll
        f32x4 acc0, acc1;
        #pragma unroll
        for (int r = 0; r < 4; ++r) {
            const int bl = m * 16 + fr_kg * 4 + r;   // batch row within tile
            float s0 = bias0, s1 = bias1;
            #pragma unroll
            for (int i = 0; i < I_SZ; ++i) {
                const float xv = x_s[bl * I_SZ + i];
                s0 += xv * wih0[i];
                s1 += xv * wih1[i];
            }
            acc0[r] = s0;
            acc1[r] = s1;
        }

        // -- group barrier: 32 wgs of our batch-split have published h_pub[t].
        //    Relaxed agent loads only; NO fences, NO cache-wide ops.
        {
            const int tgt = t + 1;
            for (;;) {
                int f = __hip_atomic_load(&flags[grp + (lane & 31)],
                                          __ATOMIC_RELAXED, __HIP_MEMORY_SCOPE_AGENT);
                if (__all(f >= tgt)) break;
                __builtin_amdgcn_s_sleep(2);
            }
            // compiler-level ordering + waitcnt only (no buffer_inv):
            __builtin_amdgcn_fence(__ATOMIC_ACQUIRE, "workgroup");
        }

        // -- h @ W_hh^T via MFMA 16x16x32 f16, K=512 (16 k-steps).
        //    A-fragments read with agent-scope relaxed u64 loads (LLC-fresh).
        {
            const unsigned long long* hb64 =
                (const unsigned long long*)(h_buf + (size_t)(t & 1) * (B_SZ * H_SZ));
            const unsigned long long* ap =
                hb64 + (((size_t)a_row * H_SZ + fr_kg * 8) >> 2);
            #pragma unroll
            for (int kk = 0; kk < 16; ++kk) {
                union { unsigned long long q[2]; f16x8 v; } au;
                au.q[0] = __hip_atomic_load(ap + kk * 8 + 0,
                                            __ATOMIC_RELAXED, __HIP_MEMORY_SCOPE_AGENT);
                au.q[1] = __hip_atomic_load(ap + kk * 8 + 1,
                                            __ATOMIC_RELAXED, __HIP_MEMORY_SCOPE_AGENT);
                acc0 = __builtin_amdgcn_mfma_f32_16x16x32_f16(au.v, wf0[kk], acc0, 0, 0, 0);
                acc1 = __builtin_amdgcn_mfma_f32_16x16x32_f16(au.v, wf1[kk], acc1, 0, 0, 0);
            }
        }

        // -- nonlinearities, exchange gate values through LDS
        #pragma unroll
        for (int r = 0; r < 4; ++r) {
            const int bl = m * 16 + fr_kg * 4 + r;
            const float p0 = acc0[r], p1 = acc1[r];
            float n0, n1;
            if (gp == 0) {          // gates i, f : sigmoid
                n0 = 1.f / (1.f + __expf(-p0));
                n1 = 1.f / (1.f + __expf(-p1));
            } else {                // gate g: tanh, gate o: sigmoid
                const float e = __expf(-2.f * p0);
                n0 = (1.f - e) / (1.f + e);
                n1 = 1.f / (1.f + __expf(-p1));
            }
            lds_g[gate0][bl][fr_col] = n0;
            lds_g[gate1][bl][fr_col] = n1;
        }
        __syncthreads();

        // -- update owned c/h cells, publish h_pub[t+1]
        {
            const float ig0 = lds_g[0][cb0][chc0],     fg0 = lds_g[1][cb0][chc0];
            const float gg0 = lds_g[2][cb0][chc0],     og0 = lds_g[3][cb0][chc0];
            const float ig1 = lds_g[0][cb0][chc0 + 1], fg1 = lds_g[1][cb0][chc0 + 1];
            const float gg1 = lds_g[2][cb0][chc0 + 1], og1 = lds_g[3][cb0][chc0 + 1];
            c0 = fg0 * c0 + ig0 * gg0;
            c1 = fg1 * c1 + ig1 * gg1;
            const float e0 = __expf(-2.f * c0), e1 = __expf(-2.f * c1);
            h0 = og0 * (1.f - e0) / (1.f + e0);
            h1 = og1 * (1.f - e1) / (1.f + e1);
            if (t < T_STEPS - 1) {
                _Float16* hbn = h_buf + (size_t)((t + 1) & 1) * (B_SZ * H_SZ);
                union { _Float16 hp[2]; unsigned u; } pk;
                pk.hp[0] = (_Float16)h0; pk.hp[1] = (_Float16)h1;
                __hip_atomic_store((unsigned*)&hbn[gb0 * H_SZ + ghc0], pk.u,
                                   __ATOMIC_RELAXED, __HIP_MEMORY_SCOPE_AGENT);
            }
        }
        // drain own h stores, then wg-wide rendezvous, then announce
        asm volatile("s_waitcnt vmcnt(0)" ::: "memory");
        __syncthreads();
        if (tid == 0 && t < T_STEPS - 1) {
            __hip_atomic_store(&flags[wg], t + 2, __ATOMIC_RELAXED, __HIP_MEMORY_SCOPE_AGENT);
        }
    }

    // ---- final outputs: (h, h, c) each [B,H] f32
    out[gb0 * H_SZ + ghc0]                  = h0;
    out[gb0 * H_SZ + ghc0 + 1]              = h1;
    out[B_SZ * H_SZ + gb0 * H_SZ + ghc0]     = h0;
    out[B_SZ * H_SZ + gb0 * H_SZ + ghc0 + 1] = h1;
    out[2 * B_SZ * H_SZ + gb0 * H_SZ + ghc0]     = c0;
    out[2 * B_SZ * H_SZ + gb0 * H_SZ + ghc0 + 1] = c1;
}

extern "C" void kernel_launch(void* const* d_in, const int* in_sizes, int n_in,
                              void* d_out, int out_size, void* d_ws, size_t ws_size,
                              hipStream_t stream) {
    const float* x    = (const float*)d_in[0];
    const float* hx   = (const float*)d_in[1];
    const float* cx   = (const float*)d_in[2];
    const float* W_ih = (const float*)d_in[3];
    const float* W_hh = (const float*)d_in[4];
    const float* b_ih = (const float*)d_in[5];
    const float* b_hh = (const float*)d_in[6];
    float* out = (float*)d_out;

    // workspace layout: [0,512) flags, [1024, 1024 + 2*B*H*2) fp16 h double-buffer
    char* ws = (char*)d_ws;
    int* flags = (int*)ws;
    _Float16* h_buf = (_Float16*)(ws + 1024);

    init_flags_kernel<<<1, 128, 0, stream>>>(flags);
    lstm_persistent<<<NWG, 256, 0, stream>>>(x, hx, cx, W_ih, W_hh, b_ih, b_hh,
                                             out, flags, h_buf);
}